// Round 2
// baseline (471.611 us; speedup 1.0000x reference)
//
#include <hip/hip_runtime.h>

#define H 128
#define CAP 64        // fixed CSR row capacity (deg ~ Poisson(16); P(deg>64) ~ 1e-18)
#define BCAP 262144   // per-range bucket capacity (expected 200k +- 0.4k; 62 sigma slack)

typedef __attribute__((ext_vector_type(8))) short bf16x8;
typedef __attribute__((ext_vector_type(4))) float f32x4;

// ---- f32 -> bf16 RTNE ----
__device__ __forceinline__ unsigned short f2bf(float f) {
  unsigned u = __float_as_uint(f);
  unsigned r = u + 0x7FFFu + ((u >> 16) & 1u);
  return (unsigned short)(r >> 16);
}
__device__ __forceinline__ float bf2f(unsigned short s) {
  return __uint_as_float(((unsigned)s) << 16);
}

// ---- merged setup: cvt x->bf16 | cvt_w^T | zero cursor | zero dummy rows | zero bcount ----
__global__ __launch_bounds__(256) void setup_all(
    const float* __restrict__ x,
    const float* __restrict__ W1, const float* __restrict__ W2, const float* __restrict__ W3,
    unsigned short* __restrict__ Xb, unsigned short* __restrict__ Wt,
    unsigned short* __restrict__ P, unsigned short* __restrict__ Q,
    int* __restrict__ cursor, int cur4, int* __restrict__ bcount,
    int n, int totalX4) {
  long long i = (long long)blockIdx.x * 256 + threadIdx.x;
  if (i < totalX4) {                     // x -> bf16 (4 elems/thread)
    float4 v = *(const float4*)(x + i * 4);
    ushort4 o;
    o.x = f2bf(v.x); o.y = f2bf(v.y); o.z = f2bf(v.z); o.w = f2bf(v.w);
    *(ushort4*)(Xb + i * 4) = o;
    return;
  }
  i -= totalX4;
  if (i < 3 * H * H) {                   // W -> bf16 transposed
    int w = (int)(i >> 14);
    int rem = (int)i & (H * H - 1);
    int c = rem >> 7;
    int k = rem & 127;
    const float* W = (w == 0) ? W1 : (w == 1) ? W2 : W3;
    Wt[i] = f2bf(W[(size_t)k * H + c]);
    return;
  }
  i -= 3 * H * H;
  if (i < cur4) {                        // zero per-node cursors (double as degree)
    *(int4*)(cursor + i * 4) = make_int4(0, 0, 0, 0);
    return;
  }
  i -= cur4;
  if (i < H) {                           // zero dummy rows (gather target index n)
    P[(size_t)n * H + i] = 0;
    Q[(size_t)n * H + i] = 0;
    return;
  }
  i -= H;
  if (i < 8) bcount[i] = 0;              // zero bucket counters
}

// ---- phase 1: single streaming pass, bin edges into 8 dst-range buckets ----
// LDS counting -> 8 global atomics per block (not per edge). Bucket id via float
// multiply: boundary mis-buckets are harmless (placement is range-agnostic).
__global__ __launch_bounds__(256) void bucket_edges(
    const int* __restrict__ src, const int* __restrict__ dst,
    int2* __restrict__ buckets, int* __restrict__ bcount,
    int ne, float invr) {
  __shared__ int cnt[8];
  __shared__ int gbase[8];
  int tid = threadIdx.x;
  if (tid < 8) cnt[tid] = 0;
  __syncthreads();

  int ne4 = ne >> 2;
  int e4 = blockIdx.x * 256 + tid;
  bool valid = e4 < ne4;
  int4 s4, d4;
  int r0 = 0, r1 = 0, r2 = 0, r3 = 0;
  int l0 = 0, l1 = 0, l2 = 0, l3 = 0;
  if (valid) {
    s4 = *(const int4*)(src + e4 * 4);
    d4 = *(const int4*)(dst + e4 * 4);
    int t;
    t = (int)((float)d4.x * invr); r0 = t < 0 ? 0 : (t > 7 ? 7 : t);
    t = (int)((float)d4.y * invr); r1 = t < 0 ? 0 : (t > 7 ? 7 : t);
    t = (int)((float)d4.z * invr); r2 = t < 0 ? 0 : (t > 7 ? 7 : t);
    t = (int)((float)d4.w * invr); r3 = t < 0 ? 0 : (t > 7 ? 7 : t);
    l0 = atomicAdd(&cnt[r0], 1);
    l1 = atomicAdd(&cnt[r1], 1);
    l2 = atomicAdd(&cnt[r2], 1);
    l3 = atomicAdd(&cnt[r3], 1);
  }
  __syncthreads();
  if (tid < 8) gbase[tid] = atomicAdd(&bcount[tid], cnt[tid]);
  __syncthreads();
  if (valid) {
    int p0 = gbase[r0] + l0;
    int p1 = gbase[r1] + l1;
    int p2 = gbase[r2] + l2;
    int p3 = gbase[r3] + l3;
    if (p0 < BCAP) buckets[(r0 << 18) + p0] = make_int2(s4.x, d4.x);
    if (p1 < BCAP) buckets[(r1 << 18) + p1] = make_int2(s4.y, d4.y);
    if (p2 < BCAP) buckets[(r2 << 18) + p2] = make_int2(s4.z, d4.z);
    if (p3 < BCAP) buckets[(r3 << 18) + p3] = make_int2(s4.w, d4.w);
  }
  // scalar tail (ne % 4)
  if (blockIdx.x == 0 && tid < (ne & 3)) {
    int e = ne4 * 4 + tid;
    int d = dst[e];
    int t = (int)((float)d * invr);
    int rr = t < 0 ? 0 : (t > 7 ? 7 : t);
    int p = atomicAdd(&bcount[rr], 1);
    if (p < BCAP) buckets[(rr << 18) + p] = make_int2(src[e], d);
  }
}

// ---- phase 2: place bucket r on XCD r (blockIdx&7); cursor/csr stay L2-local ----
__global__ __launch_bounds__(256) void place_edges(
    const int2* __restrict__ buckets, const int* __restrict__ bcount,
    int* __restrict__ cursor, int* __restrict__ csr_src, int slices) {
  int r = blockIdx.x & 7;
  int s = blockIdx.x >> 3;
  int cnt = bcount[r]; if (cnt > BCAP) cnt = BCAP;
  int chunk = (cnt + slices - 1) / slices;
  int beg = s * chunk;
  int end = beg + chunk; if (end > cnt) end = cnt;
  const int2* b = buckets + ((size_t)r << 18);
  for (int i = beg + threadIdx.x; i < end; i += 256) {
    int2 e = b[i];
    int p = atomicAdd(&cursor[e.y], 1);
    if (p < CAP) csr_src[(size_t)e.y * CAP + p] = e.x;
  }
}

// ---- merged: dinv from degree(=cursor) + graph boundaries from sorted batch ----
__global__ void dinv_gstart(const int* __restrict__ deg, float* __restrict__ dinv,
                            const int* __restrict__ batch, int* __restrict__ g_start,
                            int n, int G) {
  int i = blockIdx.x * blockDim.x + threadIdx.x;
  if (i >= n) return;
  dinv[i] = rsqrtf((float)(deg[i] + 1));
  int b = batch[i];
  int prev = (i == 0) ? -1 : batch[i - 1];
  for (int g = prev + 1; g <= b; ++g) g_start[g] = i;
  if (i == n - 1) {
    for (int g = b + 1; g <= G; ++g) g_start[g] = n;
  }
}

// ---- MFMA GEMM: out[r][:] = bf16((A @ W)[r][:] * dinv[r]); A bf16, W bf16^T ----
#define SWLD 136
__global__ __launch_bounds__(256) void gemm_mfma(
    const unsigned short* __restrict__ Ab, const unsigned short* __restrict__ Wt,
    const float* __restrict__ dinv, unsigned short* __restrict__ outb, int n) {
  __shared__ unsigned short sW[H * SWLD];
  int tid = threadIdx.x;
  {
    int c = tid >> 1, hh = tid & 1;
    const int4* s = (const int4*)(Wt + (size_t)c * H + hh * 64);
    int4* d = (int4*)(sW + (size_t)c * SWLD + hh * 64);
#pragma unroll
    for (int i = 0; i < 8; ++i) d[i] = s[i];
  }
  __syncthreads();

  int wave = tid >> 6;
  int lane = tid & 63;
  int m = lane & 15;
  int quad = lane >> 4;
  int row = blockIdx.x * 64 + wave * 16 + m;
  bool rv = row < n;

  f32x4 acc[8];
#pragma unroll
  for (int t = 0; t < 8; ++t) acc[t] = (f32x4){0.f, 0.f, 0.f, 0.f};

  const unsigned short* arow = Ab + (size_t)(rv ? row : 0) * H;
#pragma unroll
  for (int k0 = 0; k0 < H; k0 += 32) {
    bf16x8 af;
    if (rv) af = *(const bf16x8*)(arow + k0 + quad * 8);
    else    af = (bf16x8){0, 0, 0, 0, 0, 0, 0, 0};
#pragma unroll
    for (int ct = 0; ct < 8; ++ct) {
      bf16x8 bfr = *(const bf16x8*)(sW + (size_t)(ct * 16 + m) * SWLD + k0 + quad * 8);
      acc[ct] = __builtin_amdgcn_mfma_f32_16x16x32_bf16(af, bfr, acc[ct], 0, 0, 0);
    }
  }

  int orow0 = blockIdx.x * 64 + wave * 16 + quad * 4;
#pragma unroll
  for (int r = 0; r < 4; ++r) {
    int orow = orow0 + r;
    if (orow < n) {
      float dv = dinv[orow];
      unsigned short* o = outb + (size_t)orow * H + m;
#pragma unroll
      for (int ct = 0; ct < 8; ++ct) o[ct * 16] = f2bf(acc[ct][r] * dv);
    }
  }
}

// ---- bf16-input aggregate over fixed-cap CSR; f32 accumulate; bf16 or f32 out ----
// Tail group masks indices to dummy row n in-register (no CSR pad init needed).
template <bool RELU, bool OUTF32>
__global__ __launch_bounds__(256) void aggregate_bf(
    const unsigned short* __restrict__ hs, const int* __restrict__ deg_,
    const int* __restrict__ csr_src, const float* __restrict__ dinv,
    const float* __restrict__ b, void* __restrict__ outv, int n) {
  int node = blockIdx.x * 8 + (threadIdx.x >> 5);
  if (node >= n) return;
  int c = (threadIdx.x & 31) << 2;
  int deg = deg_[node]; if (deg > CAP) deg = CAP;
  int beg = node * CAP;
  int end = beg + ((deg + 7) & ~7);

  ushort4 sv = *(const ushort4*)(hs + (size_t)node * H + c);  // self row
  float4 acc;
  acc.x = bf2f(sv.x); acc.y = bf2f(sv.y); acc.z = bf2f(sv.z); acc.w = bf2f(sv.w);

  int4 ia, ib;
  if (beg < end) {
    ia = *(const int4*)(csr_src + beg);
    ib = *(const int4*)(csr_src + beg + 4);
  }
  for (int k = beg; k < end; k += 8) {
    int4 ca = ia, cb = ib;
    int kn = k + 8;
    if (kn < end) {
      ia = *(const int4*)(csr_src + kn);
      ib = *(const int4*)(csr_src + kn + 4);
    }
    int rk = k - beg;
    if (rk + 8 > deg) {                  // tail group: clamp pads to dummy row n
      ca.x = (rk + 0 < deg) ? ca.x : n;
      ca.y = (rk + 1 < deg) ? ca.y : n;
      ca.z = (rk + 2 < deg) ? ca.z : n;
      ca.w = (rk + 3 < deg) ? ca.w : n;
      cb.x = (rk + 4 < deg) ? cb.x : n;
      cb.y = (rk + 5 < deg) ? cb.y : n;
      cb.z = (rk + 6 < deg) ? cb.z : n;
      cb.w = (rk + 7 < deg) ? cb.w : n;
    }
    ushort4 v0 = *(const ushort4*)(hs + (size_t)ca.x * H + c);
    ushort4 v1 = *(const ushort4*)(hs + (size_t)ca.y * H + c);
    ushort4 v2 = *(const ushort4*)(hs + (size_t)ca.z * H + c);
    ushort4 v3 = *(const ushort4*)(hs + (size_t)ca.w * H + c);
    ushort4 v4 = *(const ushort4*)(hs + (size_t)cb.x * H + c);
    ushort4 v5 = *(const ushort4*)(hs + (size_t)cb.y * H + c);
    ushort4 v6 = *(const ushort4*)(hs + (size_t)cb.z * H + c);
    ushort4 v7 = *(const ushort4*)(hs + (size_t)cb.w * H + c);
    acc.x += ((bf2f(v0.x) + bf2f(v1.x)) + (bf2f(v2.x) + bf2f(v3.x))) +
             ((bf2f(v4.x) + bf2f(v5.x)) + (bf2f(v6.x) + bf2f(v7.x)));
    acc.y += ((bf2f(v0.y) + bf2f(v1.y)) + (bf2f(v2.y) + bf2f(v3.y))) +
             ((bf2f(v4.y) + bf2f(v5.y)) + (bf2f(v6.y) + bf2f(v7.y)));
    acc.z += ((bf2f(v0.z) + bf2f(v1.z)) + (bf2f(v2.z) + bf2f(v3.z))) +
             ((bf2f(v4.z) + bf2f(v5.z)) + (bf2f(v6.z) + bf2f(v7.z)));
    acc.w += ((bf2f(v0.w) + bf2f(v1.w)) + (bf2f(v2.w) + bf2f(v3.w))) +
             ((bf2f(v4.w) + bf2f(v5.w)) + (bf2f(v6.w) + bf2f(v7.w)));
  }

  float dv = dinv[node];
  float4 bb = *(const float4*)(b + c);
  float4 o;
  o.x = fmaf(acc.x, dv, bb.x);
  o.y = fmaf(acc.y, dv, bb.y);
  o.z = fmaf(acc.z, dv, bb.z);
  o.w = fmaf(acc.w, dv, bb.w);
  if (RELU) {
    o.x = fmaxf(o.x, 0.f); o.y = fmaxf(o.y, 0.f);
    o.z = fmaxf(o.z, 0.f); o.w = fmaxf(o.w, 0.f);
  }
  if (OUTF32) {
    *(float4*)((float*)outv + (size_t)node * H + c) = o;
  } else {
    ushort4 ob;
    ob.x = f2bf(o.x); ob.y = f2bf(o.y); ob.z = f2bf(o.z); ob.w = f2bf(o.w);
    *(ushort4*)((unsigned short*)outv + (size_t)node * H + c) = ob;
  }
}

// ---- segmented pooling, 2 blocks per graph (column halves), f32 ----
__global__ __launch_bounds__(256) void pool2(
    const float* __restrict__ h, const int* __restrict__ g_start,
    float* __restrict__ gmean, float* __restrict__ gmax, int n) {
  __shared__ float ssum[16][64];
  __shared__ float smax[16][64];
  int g = blockIdx.x >> 1;
  int half = blockIdx.x & 1;
  int beg = g_start[g];
  int end = g_start[g + 1];
  int q = threadIdx.x >> 4;
  int c = (threadIdx.x & 15) << 2;
  int cg = half * 64 + c;

  float4 s = make_float4(0.f, 0.f, 0.f, 0.f);
  float4 m = make_float4(-INFINITY, -INFINITY, -INFINITY, -INFINITY);
  for (int node = beg + q; node < end; node += 16) {
    float4 v = *(const float4*)(h + (size_t)node * H + cg);
    s.x += v.x; s.y += v.y; s.z += v.z; s.w += v.w;
    m.x = fmaxf(m.x, v.x); m.y = fmaxf(m.y, v.y);
    m.z = fmaxf(m.z, v.z); m.w = fmaxf(m.w, v.w);
  }
  *(float4*)&ssum[q][c] = s;
  *(float4*)&smax[q][c] = m;
  __syncthreads();

  int cnt = end - beg;
  int t = threadIdx.x;
  if (t < 64) {
    float tot = 0.f;
#pragma unroll
    for (int qq = 0; qq < 16; ++qq) tot += ssum[qq][t];
    gmean[(size_t)g * H + half * 64 + t] = tot / fmaxf((float)cnt, 1.0f);
  } else if (t < 128) {
    int cc = t - 64;
    float mx = -INFINITY;
#pragma unroll
    for (int qq = 0; qq < 16; ++qq) mx = fmaxf(mx, smax[qq][cc]);
    gmax[(size_t)g * H + half * 64 + cc] = (cnt == 0) ? 0.0f : mx;
  }
}

// ---- classifier: one block per graph (f32) ----
__global__ __launch_bounds__(128) void classify_kernel(
    const float* __restrict__ gmean, const float* __restrict__ gmax,
    const float* __restrict__ Wc1, const float* __restrict__ bc1,
    const float* __restrict__ Wc2, const float* __restrict__ bc2,
    float* __restrict__ out) {
  __shared__ float gv[2 * H];
  __shared__ float hid[H];
  int gid = blockIdx.x;
  int t = threadIdx.x;
  gv[t] = gmean[(size_t)gid * H + t];
  gv[H + t] = gmax[(size_t)gid * H + t];
  __syncthreads();
  float acc = 0.f;
#pragma unroll 8
  for (int k = 0; k < 2 * H; ++k) acc = fmaf(gv[k], Wc1[(size_t)k * H + t], acc);
  hid[t] = fmaxf(acc + bc1[t], 0.f);
  __syncthreads();
  if (t < 10) {
    float a2 = 0.f;
    for (int j = 0; j < H; ++j) a2 = fmaf(hid[j], Wc2[(size_t)j * 10 + t], a2);
    out[(size_t)gid * 10 + t] = a2 + bc2[t];
  }
}

extern "C" void kernel_launch(void* const* d_in, const int* in_sizes, int n_in,
                              void* d_out, int out_size, void* d_ws, size_t ws_size,
                              hipStream_t stream) {
  const float* x    = (const float*)d_in[0];
  const int* ei     = (const int*)d_in[1];
  const int* batch  = (const int*)d_in[2];
  const float* W1   = (const float*)d_in[3];
  const float* b1   = (const float*)d_in[4];
  const float* W2   = (const float*)d_in[5];
  const float* b2   = (const float*)d_in[6];
  const float* W3   = (const float*)d_in[7];
  const float* b3   = (const float*)d_in[8];
  const float* Wc1  = (const float*)d_in[9];
  const float* bc1  = (const float*)d_in[10];
  const float* Wc2  = (const float*)d_in[11];
  const float* bc2  = (const float*)d_in[12];
  float* out = (float*)d_out;

  const int n  = in_sizes[2];        // 100000 nodes
  const int ne = in_sizes[1] / 2;    // 1600000 edges
  const int G  = 512;
  const size_t NFb = (size_t)(n + 1) * H;   // +1 dummy row (bf16 tables)

  const int* src = ei;
  const int* dst = ei + ne;

  // ---- workspace layout ----
  unsigned short* P_bf = (unsigned short*)d_ws;          // h (post-agg) bf16
  unsigned short* Q_bf = P_bf + NFb;                      // h' (post-gemm) bf16
  float*          F2f  = (float*)(Q_bf + NFb);            // final h3 f32
  unsigned short* Xb   = (unsigned short*)F2f;            // x bf16 (aliases F2f)
  int* csr_src = (int*)(F2f + (size_t)n * H);
  const size_t csr_cap = (size_t)n * CAP;                 // fixed-capacity CSR
  char* p = (char*)(csr_src + csr_cap);
  int*            cursor   = (int*)p;            p += (size_t)n * 4;   // doubles as degree
  float*          dinv     = (float*)p;          p += (size_t)n * 4;
  int*            g_start  = (int*)p;            p += (size_t)(G + 1) * 4;
  float*          gmean    = (float*)p;          p += (size_t)G * H * 4;
  float*          gmax     = (float*)p;          p += (size_t)G * H * 4;
  p = (char*)(((uintptr_t)p + 255) & ~(uintptr_t)255);   // align Wt for int4 loads
  unsigned short* Wt       = (unsigned short*)p; p += (size_t)3 * H * H * 2;
  int*            bcount   = (int*)p;            p += 32;
  // buckets alias Q_bf: 8*BCAP*8B = 16.8 MB < 25.6 MB, dead until gemm1 writes it;
  // Q's dummy row (byte offset n*256 = 25.6 MB) is beyond the bucket region.
  int2*           buckets  = (int2*)Q_bf;

  // ---- merged setup ----
  {
    int totalX4 = n * H / 4;
    int cur4 = n / 4;
    long long tot = (long long)totalX4 + 3 * H * H + cur4 + H + 8;
    int blocks = (int)((tot + 255) / 256);
    setup_all<<<blocks, 256, 0, stream>>>(x, W1, W2, W3, Xb, Wt,
                                          P_bf, Q_bf, cursor, cur4, bcount, n, totalX4);
  }

  // ---- CSR build: bucket pass (coalesced, reads edges once) + XCD-local placement ----
  int range = (n + 7) / 8;
  float invr = 1.0f / (float)range;
  int bblocks = (ne / 4 + 255) / 256;
  bucket_edges<<<bblocks, 256, 0, stream>>>(src, dst, buckets, bcount, ne, invr);
  place_edges<<<8 * 256, 256, 0, stream>>>(buckets, bcount, cursor, csr_src, 256);
  dinv_gstart<<<(n + 255) / 256, 256, 0, stream>>>(cursor, dinv, batch, g_start, n, G);

  const int tile_grid = (n + 63) / 64;
  const int node_grid = (n + 7) / 8;

  // ---- layer 1 ----
  gemm_mfma<<<tile_grid, 256, 0, stream>>>(Xb, Wt, dinv, Q_bf, n);
  aggregate_bf<true, false><<<node_grid, 256, 0, stream>>>(Q_bf, cursor, csr_src, dinv, b1, P_bf, n);

  // ---- layer 2 ----
  gemm_mfma<<<tile_grid, 256, 0, stream>>>(P_bf, Wt + H * H, dinv, Q_bf, n);
  aggregate_bf<true, false><<<node_grid, 256, 0, stream>>>(Q_bf, cursor, csr_src, dinv, b2, P_bf, n);

  // ---- layer 3: bf16 gather, f32 output, no relu ----
  gemm_mfma<<<tile_grid, 256, 0, stream>>>(P_bf, Wt + 2 * H * H, dinv, Q_bf, n);
  aggregate_bf<false, true><<<node_grid, 256, 0, stream>>>(Q_bf, cursor, csr_src, dinv, b3, F2f, n);

  // ---- pooling + classifier ----
  pool2<<<2 * G, 256, 0, stream>>>(F2f, g_start, gmean, gmax, n);
  classify_kernel<<<G, 128, 0, stream>>>(gmean, gmax, Wc1, bc1, Wc2, bc2, out);
}

// Round 3
// 431.956 us; speedup vs baseline: 1.0918x; 1.0918x over previous
//
#include <hip/hip_runtime.h>

#define H 128
#define CAP 64        // fixed CSR row capacity (deg ~ Poisson(16); P(deg>64) ~ 1e-18)
#define NB 256        // nodes per bucket (bucket = dst >> 8)
#define BPCAP 6144    // per-bucket edge capacity (mean 4092, +32 sigma)
#define EPB 8192      // edges per split1 block

typedef __attribute__((ext_vector_type(8))) short bf16x8;
typedef __attribute__((ext_vector_type(4))) float f32x4;

// ---- f32 -> bf16 RTNE ----
__device__ __forceinline__ unsigned short f2bf(float f) {
  unsigned u = __float_as_uint(f);
  unsigned r = u + 0x7FFFu + ((u >> 16) & 1u);
  return (unsigned short)(r >> 16);
}
__device__ __forceinline__ float bf2f(unsigned short s) {
  return __uint_as_float(((unsigned)s) << 16);
}

// ---- merged setup: cvt x->bf16 | cvt_w^T | g_start from batch | zero dummy rows | zero bcount ----
__global__ __launch_bounds__(256) void setup_all(
    const float* __restrict__ x,
    const float* __restrict__ W1, const float* __restrict__ W2, const float* __restrict__ W3,
    unsigned short* __restrict__ Xb, unsigned short* __restrict__ Wt,
    const int* __restrict__ batch, int* __restrict__ g_start, int G,
    unsigned short* __restrict__ P, unsigned short* __restrict__ Q,
    int* __restrict__ bcount,
    int n, int totalX4) {
  long long i = (long long)blockIdx.x * 256 + threadIdx.x;
  if (i < totalX4) {                     // x -> bf16 (4 elems/thread)
    float4 v = *(const float4*)(x + i * 4);
    ushort4 o;
    o.x = f2bf(v.x); o.y = f2bf(v.y); o.z = f2bf(v.z); o.w = f2bf(v.w);
    *(ushort4*)(Xb + i * 4) = o;
    return;
  }
  i -= totalX4;
  if (i < 3 * H * H) {                   // W -> bf16 transposed
    int w = (int)(i >> 14);
    int rem = (int)i & (H * H - 1);
    int c = rem >> 7;
    int k = rem & 127;
    const float* W = (w == 0) ? W1 : (w == 1) ? W2 : W3;
    Wt[i] = f2bf(W[(size_t)k * H + c]);
    return;
  }
  i -= 3 * H * H;
  if (i < n) {                           // graph boundaries from sorted batch
    int ii = (int)i;
    int b = batch[ii];
    int prev = (ii == 0) ? -1 : batch[ii - 1];
    for (int g = prev + 1; g <= b; ++g) g_start[g] = ii;
    if (ii == n - 1) {
      for (int g = b + 1; g <= G; ++g) g_start[g] = n;
    }
    return;
  }
  i -= n;
  if (i < H) {                           // zero dummy rows (gather target index n)
    P[(size_t)n * H + i] = 0;
    Q[(size_t)n * H + i] = 0;
    return;
  }
  i -= H;
  if (i < 512) bcount[i] = 0;            // zero bucket counters
}

// ---- pass 1: partition edges into 256-node buckets; LDS histogram ->
// one global atomic per (block,bucket) (~77k total, vs 1.6M per-edge) ----
__global__ __launch_bounds__(256) void split1(
    const int* __restrict__ src, const int* __restrict__ dst,
    int2* __restrict__ buckets, int* __restrict__ bcount,
    int ne, int nbuck) {
  __shared__ int cnt[512];
  __shared__ int gbase[512];
  int tid = threadIdx.x;
  for (int i = tid; i < 512; i += 256) cnt[i] = 0;
  __syncthreads();

  int beg = blockIdx.x * EPB;
  int end = beg + EPB; if (end > ne) end = ne;

  for (int e = beg + tid; e < end; e += 256) {
    int d = dst[e];
    atomicAdd(&cnt[d >> 8], 1);
  }
  __syncthreads();
  for (int i = tid; i < nbuck; i += 256) {
    int c = cnt[i];
    gbase[i] = (c > 0) ? atomicAdd(&bcount[i], c) : 0;
    cnt[i] = 0;                          // reuse as local cursor
  }
  __syncthreads();
  for (int e = beg + tid; e < end; e += 256) {
    int s = src[e];
    int d = dst[e];                      // L2-hot reload
    int b = d >> 8;
    int l = atomicAdd(&cnt[b], 1);
    int pos = gbase[b] + l;
    if (pos < BPCAP) buckets[(size_t)b * BPCAP + pos] = make_int2(s, d);
  }
}

// ---- pass 2: one block per bucket builds per-node CSR via LDS cursors
// (zero global atomics); fuses deg + dinv output ----
__global__ __launch_bounds__(256) void build_csr(
    const int2* __restrict__ buckets, const int* __restrict__ bcount,
    int* __restrict__ csr_src, int* __restrict__ deg, float* __restrict__ dinv,
    int n) {
  __shared__ int cur[NB];
  int b = blockIdx.x;
  int tid = threadIdx.x;
  cur[tid] = 0;
  __syncthreads();
  int cntb = bcount[b]; if (cntb > BPCAP) cntb = BPCAP;
  const int2* bp = buckets + (size_t)b * BPCAP;
  for (int i = tid; i < cntb; i += 256) {
    int2 e = bp[i];
    int slot = atomicAdd(&cur[e.y & (NB - 1)], 1);   // LDS atomic
    if (slot < CAP) csr_src[(size_t)e.y * CAP + slot] = e.x;
  }
  __syncthreads();
  int node = b * NB + tid;
  if (node < n) {
    int d = cur[tid];
    deg[node] = d;
    dinv[node] = rsqrtf((float)(d + 1));
  }
}

// ---- MFMA GEMM: out[r][:] = bf16((A @ W)[r][:] * dinv[r]); A bf16, W bf16^T ----
#define SWLD 136
__global__ __launch_bounds__(256) void gemm_mfma(
    const unsigned short* __restrict__ Ab, const unsigned short* __restrict__ Wt,
    const float* __restrict__ dinv, unsigned short* __restrict__ outb, int n) {
  __shared__ unsigned short sW[H * SWLD];
  int tid = threadIdx.x;
  {
    int c = tid >> 1, hh = tid & 1;
    const int4* s = (const int4*)(Wt + (size_t)c * H + hh * 64);
    int4* d = (int4*)(sW + (size_t)c * SWLD + hh * 64);
#pragma unroll
    for (int i = 0; i < 8; ++i) d[i] = s[i];
  }
  __syncthreads();

  int wave = tid >> 6;
  int lane = tid & 63;
  int m = lane & 15;
  int quad = lane >> 4;
  int row = blockIdx.x * 64 + wave * 16 + m;
  bool rv = row < n;

  f32x4 acc[8];
#pragma unroll
  for (int t = 0; t < 8; ++t) acc[t] = (f32x4){0.f, 0.f, 0.f, 0.f};

  const unsigned short* arow = Ab + (size_t)(rv ? row : 0) * H;
#pragma unroll
  for (int k0 = 0; k0 < H; k0 += 32) {
    bf16x8 af;
    if (rv) af = *(const bf16x8*)(arow + k0 + quad * 8);
    else    af = (bf16x8){0, 0, 0, 0, 0, 0, 0, 0};
#pragma unroll
    for (int ct = 0; ct < 8; ++ct) {
      bf16x8 bfr = *(const bf16x8*)(sW + (size_t)(ct * 16 + m) * SWLD + k0 + quad * 8);
      acc[ct] = __builtin_amdgcn_mfma_f32_16x16x32_bf16(af, bfr, acc[ct], 0, 0, 0);
    }
  }

  int orow0 = blockIdx.x * 64 + wave * 16 + quad * 4;
#pragma unroll
  for (int r = 0; r < 4; ++r) {
    int orow = orow0 + r;
    if (orow < n) {
      float dv = dinv[orow];
      unsigned short* o = outb + (size_t)orow * H + m;
#pragma unroll
      for (int ct = 0; ct < 8; ++ct) o[ct * 16] = f2bf(acc[ct][r] * dv);
    }
  }
}

// ---- bf16-input aggregate over fixed-cap CSR; f32 accumulate; bf16 or f32 out ----
// Tail group masks indices to dummy row n in-register (no CSR pad init needed).
template <bool RELU, bool OUTF32>
__global__ __launch_bounds__(256) void aggregate_bf(
    const unsigned short* __restrict__ hs, const int* __restrict__ deg_,
    const int* __restrict__ csr_src, const float* __restrict__ dinv,
    const float* __restrict__ b, void* __restrict__ outv, int n) {
  int node = blockIdx.x * 8 + (threadIdx.x >> 5);
  if (node >= n) return;
  int c = (threadIdx.x & 31) << 2;
  int deg = deg_[node]; if (deg > CAP) deg = CAP;
  int beg = node * CAP;
  int end = beg + ((deg + 7) & ~7);

  ushort4 sv = *(const ushort4*)(hs + (size_t)node * H + c);  // self row
  float4 acc;
  acc.x = bf2f(sv.x); acc.y = bf2f(sv.y); acc.z = bf2f(sv.z); acc.w = bf2f(sv.w);

  int4 ia, ib;
  if (beg < end) {
    ia = *(const int4*)(csr_src + beg);
    ib = *(const int4*)(csr_src + beg + 4);
  }
  for (int k = beg; k < end; k += 8) {
    int4 ca = ia, cb = ib;
    int kn = k + 8;
    if (kn < end) {
      ia = *(const int4*)(csr_src + kn);
      ib = *(const int4*)(csr_src + kn + 4);
    }
    int rk = k - beg;
    if (rk + 8 > deg) {                  // tail group: clamp pads to dummy row n
      ca.x = (rk + 0 < deg) ? ca.x : n;
      ca.y = (rk + 1 < deg) ? ca.y : n;
      ca.z = (rk + 2 < deg) ? ca.z : n;
      ca.w = (rk + 3 < deg) ? ca.w : n;
      cb.x = (rk + 4 < deg) ? cb.x : n;
      cb.y = (rk + 5 < deg) ? cb.y : n;
      cb.z = (rk + 6 < deg) ? cb.z : n;
      cb.w = (rk + 7 < deg) ? cb.w : n;
    }
    ushort4 v0 = *(const ushort4*)(hs + (size_t)ca.x * H + c);
    ushort4 v1 = *(const ushort4*)(hs + (size_t)ca.y * H + c);
    ushort4 v2 = *(const ushort4*)(hs + (size_t)ca.z * H + c);
    ushort4 v3 = *(const ushort4*)(hs + (size_t)ca.w * H + c);
    ushort4 v4 = *(const ushort4*)(hs + (size_t)cb.x * H + c);
    ushort4 v5 = *(const ushort4*)(hs + (size_t)cb.y * H + c);
    ushort4 v6 = *(const ushort4*)(hs + (size_t)cb.z * H + c);
    ushort4 v7 = *(const ushort4*)(hs + (size_t)cb.w * H + c);
    acc.x += ((bf2f(v0.x) + bf2f(v1.x)) + (bf2f(v2.x) + bf2f(v3.x))) +
             ((bf2f(v4.x) + bf2f(v5.x)) + (bf2f(v6.x) + bf2f(v7.x)));
    acc.y += ((bf2f(v0.y) + bf2f(v1.y)) + (bf2f(v2.y) + bf2f(v3.y))) +
             ((bf2f(v4.y) + bf2f(v5.y)) + (bf2f(v6.y) + bf2f(v7.y)));
    acc.z += ((bf2f(v0.z) + bf2f(v1.z)) + (bf2f(v2.z) + bf2f(v3.z))) +
             ((bf2f(v4.z) + bf2f(v5.z)) + (bf2f(v6.z) + bf2f(v7.z)));
    acc.w += ((bf2f(v0.w) + bf2f(v1.w)) + (bf2f(v2.w) + bf2f(v3.w))) +
             ((bf2f(v4.w) + bf2f(v5.w)) + (bf2f(v6.w) + bf2f(v7.w)));
  }

  float dv = dinv[node];
  float4 bb = *(const float4*)(b + c);
  float4 o;
  o.x = fmaf(acc.x, dv, bb.x);
  o.y = fmaf(acc.y, dv, bb.y);
  o.z = fmaf(acc.z, dv, bb.z);
  o.w = fmaf(acc.w, dv, bb.w);
  if (RELU) {
    o.x = fmaxf(o.x, 0.f); o.y = fmaxf(o.y, 0.f);
    o.z = fmaxf(o.z, 0.f); o.w = fmaxf(o.w, 0.f);
  }
  if (OUTF32) {
    *(float4*)((float*)outv + (size_t)node * H + c) = o;
  } else {
    ushort4 ob;
    ob.x = f2bf(o.x); ob.y = f2bf(o.y); ob.z = f2bf(o.z); ob.w = f2bf(o.w);
    *(ushort4*)((unsigned short*)outv + (size_t)node * H + c) = ob;
  }
}

// ---- segmented pooling, 2 blocks per graph (column halves), f32 ----
__global__ __launch_bounds__(256) void pool2(
    const float* __restrict__ h, const int* __restrict__ g_start,
    float* __restrict__ gmean, float* __restrict__ gmax, int n) {
  __shared__ float ssum[16][64];
  __shared__ float smax[16][64];
  int g = blockIdx.x >> 1;
  int half = blockIdx.x & 1;
  int beg = g_start[g];
  int end = g_start[g + 1];
  int q = threadIdx.x >> 4;
  int c = (threadIdx.x & 15) << 2;
  int cg = half * 64 + c;

  float4 s = make_float4(0.f, 0.f, 0.f, 0.f);
  float4 m = make_float4(-INFINITY, -INFINITY, -INFINITY, -INFINITY);
  for (int node = beg + q; node < end; node += 16) {
    float4 v = *(const float4*)(h + (size_t)node * H + cg);
    s.x += v.x; s.y += v.y; s.z += v.z; s.w += v.w;
    m.x = fmaxf(m.x, v.x); m.y = fmaxf(m.y, v.y);
    m.z = fmaxf(m.z, v.z); m.w = fmaxf(m.w, v.w);
  }
  *(float4*)&ssum[q][c] = s;
  *(float4*)&smax[q][c] = m;
  __syncthreads();

  int cnt = end - beg;
  int t = threadIdx.x;
  if (t < 64) {
    float tot = 0.f;
#pragma unroll
    for (int qq = 0; qq < 16; ++qq) tot += ssum[qq][t];
    gmean[(size_t)g * H + half * 64 + t] = tot / fmaxf((float)cnt, 1.0f);
  } else if (t < 128) {
    int cc = t - 64;
    float mx = -INFINITY;
#pragma unroll
    for (int qq = 0; qq < 16; ++qq) mx = fmaxf(mx, smax[qq][cc]);
    gmax[(size_t)g * H + half * 64 + cc] = (cnt == 0) ? 0.0f : mx;
  }
}

// ---- classifier: one block per graph (f32) ----
__global__ __launch_bounds__(128) void classify_kernel(
    const float* __restrict__ gmean, const float* __restrict__ gmax,
    const float* __restrict__ Wc1, const float* __restrict__ bc1,
    const float* __restrict__ Wc2, const float* __restrict__ bc2,
    float* __restrict__ out) {
  __shared__ float gv[2 * H];
  __shared__ float hid[H];
  int gid = blockIdx.x;
  int t = threadIdx.x;
  gv[t] = gmean[(size_t)gid * H + t];
  gv[H + t] = gmax[(size_t)gid * H + t];
  __syncthreads();
  float acc = 0.f;
#pragma unroll 8
  for (int k = 0; k < 2 * H; ++k) acc = fmaf(gv[k], Wc1[(size_t)k * H + t], acc);
  hid[t] = fmaxf(acc + bc1[t], 0.f);
  __syncthreads();
  if (t < 10) {
    float a2 = 0.f;
    for (int j = 0; j < H; ++j) a2 = fmaf(hid[j], Wc2[(size_t)j * 10 + t], a2);
    out[(size_t)gid * 10 + t] = a2 + bc2[t];
  }
}

extern "C" void kernel_launch(void* const* d_in, const int* in_sizes, int n_in,
                              void* d_out, int out_size, void* d_ws, size_t ws_size,
                              hipStream_t stream) {
  const float* x    = (const float*)d_in[0];
  const int* ei     = (const int*)d_in[1];
  const int* batch  = (const int*)d_in[2];
  const float* W1   = (const float*)d_in[3];
  const float* b1   = (const float*)d_in[4];
  const float* W2   = (const float*)d_in[5];
  const float* b2   = (const float*)d_in[6];
  const float* W3   = (const float*)d_in[7];
  const float* b3   = (const float*)d_in[8];
  const float* Wc1  = (const float*)d_in[9];
  const float* bc1  = (const float*)d_in[10];
  const float* Wc2  = (const float*)d_in[11];
  const float* bc2  = (const float*)d_in[12];
  float* out = (float*)d_out;

  const int n  = in_sizes[2];        // 100000 nodes
  const int ne = in_sizes[1] / 2;    // 1600000 edges
  const int G  = 512;
  const size_t NFb = (size_t)(n + 1) * H;   // +1 dummy row (bf16 tables)

  const int* src = ei;
  const int* dst = ei + ne;

  // ---- workspace layout ----
  unsigned short* P_bf = (unsigned short*)d_ws;          // h (post-agg) bf16
  unsigned short* Q_bf = P_bf + NFb;                      // h' (post-gemm) bf16
  float*          F2f  = (float*)(Q_bf + NFb);            // final h3 f32
  unsigned short* Xb   = (unsigned short*)F2f;            // x bf16 (aliases F2f)
  int* csr_src = (int*)(F2f + (size_t)n * H);
  const size_t csr_cap = (size_t)n * CAP;                 // fixed-capacity CSR
  char* p = (char*)(csr_src + csr_cap);
  int*            deg      = (int*)p;            p += (size_t)n * 4;
  float*          dinv     = (float*)p;          p += (size_t)n * 4;
  int*            g_start  = (int*)p;            p += (size_t)(G + 1) * 4;
  float*          gmean    = (float*)p;          p += (size_t)G * H * 4;
  float*          gmax     = (float*)p;          p += (size_t)G * H * 4;
  p = (char*)(((uintptr_t)p + 255) & ~(uintptr_t)255);   // align Wt for int4 loads
  unsigned short* Wt       = (unsigned short*)p; p += (size_t)3 * H * H * 2;
  int*            bcount   = (int*)p;            p += 512 * 4;
  // buckets alias Q_bf: nbuck*BPCAP*8B = 19.2 MB < 25.6 MB, dead until gemm1;
  // Q's dummy row (byte offset n*256 = 25.6 MB) is beyond the bucket region.
  int2*           buckets  = (int2*)Q_bf;

  const int nbuck = (n + NB - 1) / NB;   // 391

  // ---- merged setup (incl. g_start scan; no per-node cursor zeroing needed) ----
  {
    int totalX4 = n * H / 4;
    long long tot = (long long)totalX4 + 3 * H * H + n + H + 512;
    int blocks = (int)((tot + 255) / 256);
    setup_all<<<blocks, 256, 0, stream>>>(x, W1, W2, W3, Xb, Wt,
                                          batch, g_start, G,
                                          P_bf, Q_bf, bcount, n, totalX4);
  }

  // ---- CSR build: LDS-histogram partition + LDS-cursor placement (no per-edge
  // global atomics; csr_fill/place were atomic-throughput-bound at ~1/cy/XCD) ----
  split1<<<(ne + EPB - 1) / EPB, 256, 0, stream>>>(src, dst, buckets, bcount, ne, nbuck);
  build_csr<<<nbuck, 256, 0, stream>>>(buckets, bcount, csr_src, deg, dinv, n);

  const int tile_grid = (n + 63) / 64;
  const int node_grid = (n + 7) / 8;

  // ---- layer 1 ----
  gemm_mfma<<<tile_grid, 256, 0, stream>>>(Xb, Wt, dinv, Q_bf, n);
  aggregate_bf<true, false><<<node_grid, 256, 0, stream>>>(Q_bf, deg, csr_src, dinv, b1, P_bf, n);

  // ---- layer 2 ----
  gemm_mfma<<<tile_grid, 256, 0, stream>>>(P_bf, Wt + H * H, dinv, Q_bf, n);
  aggregate_bf<true, false><<<node_grid, 256, 0, stream>>>(Q_bf, deg, csr_src, dinv, b2, P_bf, n);

  // ---- layer 3: bf16 gather, f32 output, no relu ----
  gemm_mfma<<<tile_grid, 256, 0, stream>>>(P_bf, Wt + 2 * H * H, dinv, Q_bf, n);
  aggregate_bf<false, true><<<node_grid, 256, 0, stream>>>(Q_bf, deg, csr_src, dinv, b3, F2f, n);

  // ---- pooling + classifier ----
  pool2<<<2 * G, 256, 0, stream>>>(F2f, g_start, gmean, gmax, n);
  classify_kernel<<<G, 128, 0, stream>>>(gmean, gmax, Wc1, bc1, Wc2, bc2, out);
}